// Round 16
// baseline (2762.439 us; speedup 1.0000x reference)
//
#include <hip/hip_runtime.h>
#include <math.h>

#define D_IN   512
#define HID    1024
#define SEQ    512
#define NBATCH 64
#define K3     3072
#define KTOT   1536
#define WB_ELEMS (K3 * KTOT)
#define NBLK   256
#define BLOCK_T 512   // 8 waves; each owns h K=128 (fp16) + x K=64 (bf16), weights in VGPR

typedef __attribute__((ext_vector_type(8))) short short8;
typedef __attribute__((ext_vector_type(4))) float f32x4;
typedef __attribute__((ext_vector_type(4))) unsigned u32x4;
typedef _Float16 half8 __attribute__((ext_vector_type(8)));

#define MFMA_BF16(a, b, c) __builtin_amdgcn_mfma_f32_16x16x32_bf16((a), (b), (c), 0, 0, 0)
#define MFMA_F16(a, b, c)  __builtin_amdgcn_mfma_f32_16x16x32_f16((a), (b), (c), 0, 0, 0)

// ---------------- build fused transposed weight planes ----------------
// [col 0..3071][k 0..1535]; k<512 (x-part): bf16 hi/lo bits; k>=512 (h-part): fp16 hi/lo bits.
__global__ __launch_bounds__(256) void build_wt(const float* __restrict__ Win,
                                                const float* __restrict__ Wh,
                                                unsigned short* __restrict__ WBh,
                                                unsigned short* __restrict__ WBl) {
    int idx = blockIdx.x * 256 + threadIdx.x;
    if (idx >= WB_ELEMS) return;
    int k   = idx % KTOT;
    int col = idx / KTOT;
    float v = (k < D_IN) ? Win[(size_t)k * K3 + col]
                         : Wh[(size_t)(k - D_IN) * K3 + col];
    unsigned short hb, lb;
    if (k < D_IN) {
        __bf16 h = (__bf16)v;
        hb = __builtin_bit_cast(unsigned short, h);
        lb = __builtin_bit_cast(unsigned short, (__bf16)(v - (float)h));
    } else {
        _Float16 h = (_Float16)v;
        hb = __builtin_bit_cast(unsigned short, h);
        lb = __builtin_bit_cast(unsigned short, (_Float16)(v - (float)h));
    }
    WBh[idx] = hb;
    WBl[idx] = lb;
}

__device__ __forceinline__ void cvt8(const f32x4& v0, const f32x4& v1,
                                     short8& ahi, short8& alo) {
    float af[8] = {v0[0], v0[1], v0[2], v0[3], v1[0], v1[1], v1[2], v1[3]};
    #pragma unroll
    for (int j = 0; j < 8; ++j) {
        __bf16 hb = (__bf16)af[j];
        __bf16 lb = (__bf16)(af[j] - (float)hb);
        ahi[j] = __builtin_bit_cast(short, hb);
        alo[j] = __builtin_bit_cast(short, lb);
    }
}

// ---------------- persistent GRU: merged waves + x-prefetch ----------------
// Grid 256 x 512 (8 waves, 2/SIMD, VGPR cap 256). Block (mq=j&3, nb=xcd+8*(j>>2)).
// Wave w: h-slice [512+128w,+128) fp16 reg-weights + x-slice [64w,+64) bf16
// reg-weights (144 VGPR total). Step order: h-poll/load/MFMA -> x-cvt/MFMA
// (data prefetched LAST step) -> red(z,r,nh,nx) -> sync -> epilogue.
// x-prefetch for t+1 is issued strictly POST-sync (pre-sync issue would stall
// __syncthreads' implicit vmcnt(0) drain): waves 0-3 issue it after their flag
// store; waves 4-7 right after sync. Its latency hides under the next poll
// (flags appear ~1us after sync anyway). Exchange protocol identical to r15
// (fragment-order hx3, drain-then-flag, ballot streaming consume, ring-2).
__global__ __attribute__((amdgpu_waves_per_eu(2, 2)))
__launch_bounds__(BLOCK_T) void gru_persist(
        const float* __restrict__ x, const float* __restrict__ bin,
        const unsigned short* __restrict__ WBh, const unsigned short* __restrict__ WBl,
        float* __restrict__ out, unsigned short* __restrict__ hx3,
        unsigned* __restrict__ flags) {
    __shared__ float red[2][8][4][4][64];   // 64 KB, double-buffered; gates z,r,nh,nx
    float* hall = out + NBATCH * HID;

    const int tid = threadIdx.x;
    const int l   = tid & 63;
    const int w   = tid >> 6;              // 0..7
    const int xcd = blockIdx.x & 7;
    const int j   = blockIdx.x >> 3;
    const int nb  = xcd + 8 * (j >> 2);
    const int mq  = j & 3;
    const int cb  = nb * 16;

    const int m      = mq * 16 + (l & 15);
    const int koff   = (l >> 4) * 8;
    const int colz   = cb + (l & 15);
    const int kbase  = D_IN + 128 * w;     // h-slice
    const int kxbase = 64 * w;             // x-slice

    const unsigned* fpal = flags + ((size_t)mq * 64 + 8 * w) * 4 + (l & 31);

    // ---- one-time weights -> registers: h (fp16 bits) + x (bf16 bits)
    short8 Bh[3][4], Bl[3][4], Bxh[3][2], Bxl[3][2];
    #pragma unroll
    for (int g = 0; g < 3; ++g) {
        #pragma unroll
        for (int s = 0; s < 4; ++s) {
            const size_t o = (size_t)(colz + g * HID) * KTOT + kbase + 32 * s + koff;
            Bh[g][s] = *(const short8*)(WBh + o);
            Bl[g][s] = *(const short8*)(WBl + o);
        }
        #pragma unroll
        for (int s = 0; s < 2; ++s) {
            const size_t o = (size_t)(colz + g * HID) * KTOT + kxbase + 32 * s + koff;
            Bxh[g][s] = *(const short8*)(WBh + o);
            Bxl[g][s] = *(const short8*)(WBl + o);
        }
    }
    #pragma unroll
    for (int g = 0; g < 3; ++g) {
        #pragma unroll
        for (int s = 0; s < 4; ++s) {
            asm volatile("" : "+v"(Bh[g][s]));
            asm volatile("" : "+v"(Bl[g][s]));
        }
        #pragma unroll
        for (int s = 0; s < 2; ++s) {
            asm volatile("" : "+v"(Bxh[g][s]));
            asm volatile("" : "+v"(Bxl[g][s]));
        }
    }

    // epilogue constants (waves 0-3)
    const int r2 = tid >> 6;
    const int l2 = tid & 63;
    const int be = mq * 16 + (l2 >> 4) * 4 + r2;   // C layout (m89)
    const int ce = cb + (l2 & 15);
    float bz = 0.f, br = 0.f, bnb = 0.f, hreg = 0.f;
    unsigned* fprod = flags + ((size_t)mq * 64 + nb) * 4 + r2;
    const int p_w  = nb >> 3;
    const int p_si = (nb & 7) >> 1;
    const int p_g  = ((nb & 1) << 1) | ((l2 >> 3) & 1);
    const int p_e  = l2 & 7;
    const int p_b  = (l2 >> 4) * 4 + r2;
    const size_t p_off = (size_t)((p_si * 4 + p_g) * 16 + p_b) * 8 + p_e;
    if (tid < 256) {
        bz  = bin[ce];
        br  = bin[HID + ce];
        bnb = bin[2 * HID + ce];
    }
    asm volatile("" : "+v"(bz), "+v"(br), "+v"(bnb));

    // ---- preamble: issue x(t=0) loads (consumed at first x-cvt)
    f32x4 xv0, xv1, xv2, xv3;
    {
        const float* xp = x + (size_t)m * SEQ * D_IN + kxbase + koff;
        asm volatile(
            "global_load_dwordx4 %0, %4, off\n\t"
            "global_load_dwordx4 %1, %4, off offset:16\n\t"
            "global_load_dwordx4 %2, %4, off offset:128\n\t"
            "global_load_dwordx4 %3, %4, off offset:144"
            : "=&v"(xv0), "=&v"(xv1), "=&v"(xv2), "=&v"(xv3)
            : "v"(xp));
    }

    for (int t = 0; t < SEQ; ++t) {
        f32x4 aZ = {0.f,0.f,0.f,0.f}, aR = {0.f,0.f,0.f,0.f};
        f32x4 aNH = {0.f,0.f,0.f,0.f}, aNX = {0.f,0.f,0.f,0.f};

        // ---- h-part: poll + streaming load + f16 MFMA
        if (t > 0) {
            const unsigned tagexp = (unsigned)t;
            const unsigned short* hp = hx3
                + ((size_t)(((t - 1) & 1) * 4 + mq) * 8 + w) * 2048
                + (size_t)l * 8;
            u32x4 q0 = {0,0,0,0}, q1 = {0,0,0,0}, q2 = {0,0,0,0}, q3 = {0,0,0,0};
            unsigned need = 0xFu;
            while (true) {
                unsigned f;
                asm volatile("global_load_dword %0, %1, off sc0 sc1\n\t"
                             "s_waitcnt vmcnt(0)"
                             : "=v"(f) : "v"(fpal));
                unsigned long long rdy = __ballot(f >= tagexp);
                if ((need & 1u) && (((rdy >> 0)  & 0xFFull) == 0xFFull)) {
                    asm volatile("global_load_dwordx4 %0, %1, off sc0 sc1"
                                 : "=&v"(q0) : "v"(hp));
                    need &= ~1u;
                }
                if ((need & 2u) && (((rdy >> 8)  & 0xFFull) == 0xFFull)) {
                    asm volatile("global_load_dwordx4 %0, %1, off offset:1024 sc0 sc1"
                                 : "=&v"(q1) : "v"(hp));
                    need &= ~2u;
                }
                if ((need & 4u) && (((rdy >> 16) & 0xFFull) == 0xFFull)) {
                    asm volatile("global_load_dwordx4 %0, %1, off offset:2048 sc0 sc1"
                                 : "=&v"(q2) : "v"(hp));
                    need &= ~4u;
                }
                if ((need & 8u) && (((rdy >> 24) & 0xFFull) == 0xFFull)) {
                    asm volatile("global_load_dwordx4 %0, %1, off offset:3072 sc0 sc1"
                                 : "=&v"(q3) : "v"(hp));
                    need &= ~8u;
                }
                if (!need) break;
                __builtin_amdgcn_s_sleep(1);
            }
            asm volatile("s_waitcnt vmcnt(0)"
                         : "+v"(q0), "+v"(q1), "+v"(q2), "+v"(q3));
            __builtin_amdgcn_sched_barrier(0);
            #define SUBT16(si, q) { \
                half8 ah = __builtin_bit_cast(half8, (q)); \
                aZ  = MFMA_F16(ah, __builtin_bit_cast(half8, Bh[0][si]), aZ); \
                aZ  = MFMA_F16(ah, __builtin_bit_cast(half8, Bl[0][si]), aZ); \
                aR  = MFMA_F16(ah, __builtin_bit_cast(half8, Bh[1][si]), aR); \
                aR  = MFMA_F16(ah, __builtin_bit_cast(half8, Bl[1][si]), aR); \
                aNH = MFMA_F16(ah, __builtin_bit_cast(half8, Bh[2][si]), aNH); \
                aNH = MFMA_F16(ah, __builtin_bit_cast(half8, Bl[2][si]), aNH); }
            SUBT16(0, q0)
            SUBT16(1, q1)
            SUBT16(2, q2)
            SUBT16(3, q3)
            #undef SUBT16
        }

        // ---- x-part: consume prefetched registers (bf16 hi/lo, 3-MFMA split)
        asm volatile("s_waitcnt vmcnt(0)"
                     : "+v"(xv0), "+v"(xv1), "+v"(xv2), "+v"(xv3));
        __builtin_amdgcn_sched_barrier(0);
        #pragma unroll
        for (int s = 0; s < 2; ++s) {
            short8 ahi, alo;
            cvt8((s == 0) ? xv0 : xv2, (s == 0) ? xv1 : xv3, ahi, alo);
            aZ  = MFMA_BF16(ahi, Bxh[0][s], aZ);  aZ  = MFMA_BF16(ahi, Bxl[0][s], aZ);
            aZ  = MFMA_BF16(alo, Bxh[0][s], aZ);
            aR  = MFMA_BF16(ahi, Bxh[1][s], aR);  aR  = MFMA_BF16(ahi, Bxl[1][s], aR);
            aR  = MFMA_BF16(alo, Bxh[1][s], aR);
            aNX = MFMA_BF16(ahi, Bxh[2][s], aNX); aNX = MFMA_BF16(ahi, Bxl[2][s], aNX);
            aNX = MFMA_BF16(alo, Bxh[2][s], aNX);
        }

        const int buf = t & 1;
        #pragma unroll
        for (int r = 0; r < 4; ++r) {
            red[buf][w][0][r][l] = aZ[r];
            red[buf][w][1][r][l] = aR[r];
            red[buf][w][2][r][l] = aNH[r];
            red[buf][w][3][r][l] = aNX[r];
        }
        __syncthreads();   // red[t] published (single barrier per step)

        const int tp = (t + 1 < SEQ) ? t + 1 : SEQ - 1;   // prefetch row (clamped)
        const float* xpn = x + ((size_t)m * SEQ + tp) * D_IN + kxbase + koff;

        if (tid < 256) {
            float sz = 0.f, sr = 0.f, snh = 0.f, snx = 0.f;
            #pragma unroll
            for (int wv = 0; wv < 8; ++wv) {
                sz  += red[buf][wv][0][r2][l2];
                sr  += red[buf][wv][1][r2][l2];
                snh += red[buf][wv][2][r2][l2];
                snx += red[buf][wv][3][r2][l2];
            }
            float z   = 1.f / (1.f + __expf(-(sz + bz)));
            float rr  = 1.f / (1.f + __expf(-(sr + br)));
            float pre = snx + bnb + rr * snh;
            float e2  = __expf(2.f * pre);
            float n   = 1.f - 2.f / (e2 + 1.f);
            float h   = (1.f - z) * n + z * hreg;
            hreg = h;

            // fragment-order fp16 data store -> drain (data at L3) -> flag
            unsigned hv = (unsigned)__builtin_bit_cast(unsigned short, (_Float16)h);
            unsigned short* hxp = hx3
                + ((size_t)((t & 1) * 4 + mq) * 8 + p_w) * 2048 + p_off;
            asm volatile("global_store_short %0, %1, off sc0 sc1"
                         :: "v"(hxp), "v"(hv) : "memory");
            asm volatile("s_waitcnt vmcnt(0)" ::: "memory");
            if ((tid & 63) == 0) {
                unsigned fv = (unsigned)(t + 1);
                asm volatile("global_store_dword %0, %1, off sc0 sc1"
                             :: "v"(fprod), "v"(fv) : "memory");
            }
            // x-prefetch for t+1 (post-flag: never delays the critical flag)
            asm volatile(
                "global_load_dwordx4 %0, %4, off\n\t"
                "global_load_dwordx4 %1, %4, off offset:16\n\t"
                "global_load_dwordx4 %2, %4, off offset:128\n\t"
                "global_load_dwordx4 %3, %4, off offset:144"
                : "=&v"(xv0), "=&v"(xv1), "=&v"(xv2), "=&v"(xv3)
                : "v"(xpn));
            // archival fp32 writes: off critical path, normal cached stores
            hall[((size_t)be * SEQ + t) * HID + ce] = h;
            if (t == SEQ - 1) out[(size_t)be * HID + ce] = h;
        } else {
            // waves 4-7: x-prefetch immediately post-sync; latency hides under
            // the next poll (flags appear ~1us after sync anyway)
            asm volatile(
                "global_load_dwordx4 %0, %4, off\n\t"
                "global_load_dwordx4 %1, %4, off offset:16\n\t"
                "global_load_dwordx4 %2, %4, off offset:128\n\t"
                "global_load_dwordx4 %3, %4, off offset:144"
                : "=&v"(xv0), "=&v"(xv1), "=&v"(xv2), "=&v"(xv3)
                : "v"(xpn));
        }
    }
}

extern "C" void kernel_launch(void* const* d_in, const int* in_sizes, int n_in,
                              void* d_out, int out_size, void* d_ws, size_t ws_size,
                              hipStream_t stream) {
    const float* x   = (const float*)d_in[0];
    const float* Win = (const float*)d_in[1];
    const float* bin = (const float*)d_in[2];
    const float* Wh  = (const float*)d_in[3];
    float* out = (float*)d_out;

    unsigned short* WBh = (unsigned short*)d_ws;                       // 9.44 MB
    unsigned short* WBl = (unsigned short*)d_ws + (size_t)WB_ELEMS;    // 9.44 MB
    const size_t hx_off = ((size_t)2 * WB_ELEMS * sizeof(unsigned short) + (1u << 20))
                          & ~((size_t)(1u << 20) - 1);                 // 1MB-aligned
    unsigned* flags      = (unsigned*)((char*)d_ws + hx_off);          // 4 KB
    unsigned short* hx3  = (unsigned short*)((char*)d_ws + hx_off + 65536); // 256 KB

    hipMemsetAsync(flags, 0, 4096, stream);   // replay-safe (hx3 is flag-gated)
    hipLaunchKernelGGL(build_wt, dim3((WB_ELEMS + 255) / 256), dim3(256), 0, stream,
                       Win, Wh, WBh, WBl);
    hipLaunchKernelGGL(gru_persist, dim3(NBLK), dim3(BLOCK_T), 0, stream,
                       x, bin, WBh, WBl, out, hx3, flags);
}

// Round 17
// 2407.295 us; speedup vs baseline: 1.1475x; 1.1475x over previous
//
#include <hip/hip_runtime.h>
#include <math.h>

#define D_IN   512
#define HID    1024
#define SEQ    512
#define NBATCH 64
#define K3     3072
#define KTOT   1536
#define WB_ELEMS (K3 * KTOT)
#define NBLK   256
#define BLOCK_T 768   // 12 waves: 0-7 h-part (fp16, K=128 each), 8-11 x-part (bf16, K=128)

typedef __attribute__((ext_vector_type(8))) short short8;
typedef __attribute__((ext_vector_type(4))) float f32x4;
typedef __attribute__((ext_vector_type(4))) unsigned u32x4;
typedef _Float16 half8 __attribute__((ext_vector_type(8)));

#define MFMA_BF16(a, b, c) __builtin_amdgcn_mfma_f32_16x16x32_bf16((a), (b), (c), 0, 0, 0)
#define MFMA_F16(a, b, c)  __builtin_amdgcn_mfma_f32_16x16x32_f16((a), (b), (c), 0, 0, 0)

// ---------------- build fused transposed weight planes ----------------
// [col 0..3071][k 0..1535]; k<512 (x-part): bf16 hi/lo bits; k>=512 (h-part): fp16 hi/lo bits.
__global__ __launch_bounds__(256) void build_wt(const float* __restrict__ Win,
                                                const float* __restrict__ Wh,
                                                unsigned short* __restrict__ WBh,
                                                unsigned short* __restrict__ WBl) {
    int idx = blockIdx.x * 256 + threadIdx.x;
    if (idx >= WB_ELEMS) return;
    int k   = idx % KTOT;
    int col = idx / KTOT;
    float v = (k < D_IN) ? Win[(size_t)k * K3 + col]
                         : Wh[(size_t)(k - D_IN) * K3 + col];
    unsigned short hb, lb;
    if (k < D_IN) {
        __bf16 h = (__bf16)v;
        hb = __builtin_bit_cast(unsigned short, h);
        lb = __builtin_bit_cast(unsigned short, (__bf16)(v - (float)h));
    } else {
        _Float16 h = (_Float16)v;
        hb = __builtin_bit_cast(unsigned short, h);
        lb = __builtin_bit_cast(unsigned short, (_Float16)(v - (float)h));
    }
    WBh[idx] = hb;
    WBl[idx] = lb;
}

__device__ __forceinline__ void cvt8(const f32x4& v0, const f32x4& v1,
                                     short8& ahi, short8& alo) {
    float af[8] = {v0[0], v0[1], v0[2], v0[3], v1[0], v1[1], v1[2], v1[3]};
    #pragma unroll
    for (int j = 0; j < 8; ++j) {
        __bf16 hb = (__bf16)af[j];
        __bf16 lb = (__bf16)(af[j] - (float)hb);
        ahi[j] = __builtin_bit_cast(short, hb);
        alo[j] = __builtin_bit_cast(short, lb);
    }
}

// ---------------- persistent GRU: fragment-order exchange + streaming consume ----------------
// (round-15 design, reverted after round-16's merged-wave regression: vmcnt is a
// per-wave counter over ALL vmem ops, so mixing x-prefetch into consumer waves
// serialized x HBM latency into the flag poll; keep x in dedicated waves.)
// hx3[slot][mq][w] = contiguous 4KB wave-block holding h[t] (fp16) in EXACT
// f16-MFMA A-fragment order (half idx = ((si*4+g)*16+b)*8+e). Producer wave:
// 64 fp16 stores (sc0sc1) -> vmcnt(0) drain -> flag = t+1 (sc0sc1).
// Skew absorption: subtile si of consumer wave w depends ONLY on producer
// blocks {8w+2si, 8w+2si+1}. Ballot-based streaming loop: each iteration
// re-loads the 32 flags (2 cache lines), computes per-pair readiness via
// __ballot, and ISSUES subtile si's dwordx4 the moment its pair is ready.
// Final vmcnt(0) is register-tied ("+v") so MFMAs can't hoist (rule 18).
// Ring-2 WAR proof: P's step-t+2 overwrite of slot t&1 is gated (flag union
// over its 8 h-waves = all 64 blocks) on every block's step-t+1 loads having
// returned (loads complete before that block's t+1 flag).
__global__ __attribute__((amdgpu_waves_per_eu(3, 3)))
__launch_bounds__(BLOCK_T) void gru_persist(
        const float* __restrict__ x, const float* __restrict__ bin,
        const unsigned short* __restrict__ WBh, const unsigned short* __restrict__ WBl,
        float* __restrict__ out, unsigned short* __restrict__ hx3,
        unsigned* __restrict__ flags) {
    __shared__ float red[2][12][3][4][64];   // 72 KB, double-buffered
    float* hall = out + NBATCH * HID;

    const int tid = threadIdx.x;
    const int l   = tid & 63;
    const int w   = tid >> 6;              // 0..11
    const int xcd = blockIdx.x & 7;
    const int j   = blockIdx.x >> 3;
    const int nb  = xcd + 8 * (j >> 2);
    const int mq  = j & 3;
    const int cb  = nb * 16;

    const int m    = mq * 16 + (l & 15);
    const int koff = (l >> 4) * 8;
    const int colz = cb + (l & 15);
    const bool isH = (w < 8);
    const int kbase = isH ? (D_IN + 128 * w) : (128 * (w - 8));

    // consumer flag addrs: producer blocks 8w..8w+7 of my domain, epi-waves 0-3
    // lane l reads flag word (l&31): block 8w + ((l&31)>>2), wave (l&3)
    const unsigned* fpal = flags + ((size_t)mq * 64 + 8 * w) * 4 + (l & 31);

    // ---- one-time weight slice -> registers (h-part fp16 bits, x-part bf16 bits)
    short8 Bh[3][4], Bl[3][4];
    #pragma unroll
    for (int g = 0; g < 3; ++g) {
        #pragma unroll
        for (int s = 0; s < 4; ++s) {
            const size_t o = (size_t)(colz + g * HID) * KTOT + kbase + 32 * s + koff;
            Bh[g][s] = *(const short8*)(WBh + o);
            Bl[g][s] = *(const short8*)(WBl + o);
        }
    }
    #pragma unroll
    for (int g = 0; g < 3; ++g) {
        #pragma unroll
        for (int s = 0; s < 4; ++s) {
            asm volatile("" : "+v"(Bh[g][s]));
            asm volatile("" : "+v"(Bl[g][s]));
        }
    }

    // epilogue constants (waves 0-3)
    const int r2 = tid >> 6;
    const int l2 = tid & 63;
    const int be = mq * 16 + (l2 >> 4) * 4 + r2;   // C layout (m89)
    const int ce = cb + (l2 & 15);
    float bz = 0.f, br = 0.f, bnb = 0.f, hreg = 0.f;
    unsigned* fprod = flags + ((size_t)mq * 64 + nb) * 4 + r2;
    // producer scatter target inside destination wave-block (fragment order)
    const int p_w  = nb >> 3;                         // dest k-slice wave
    const int p_si = (nb & 7) >> 1;                   // 32-k subtile
    const int p_g  = ((nb & 1) << 1) | ((l2 >> 3) & 1);
    const int p_e  = l2 & 7;
    const int p_b  = (l2 >> 4) * 4 + r2;              // be & 15
    const size_t p_off = (size_t)((p_si * 4 + p_g) * 16 + p_b) * 8 + p_e;
    if (tid < 256) {
        bz  = bin[ce];
        br  = bin[HID + ce];
        bnb = bin[2 * HID + ce];
    }
    asm volatile("" : "+v"(bz), "+v"(br), "+v"(bnb));

    for (int t = 0; t < SEQ; ++t) {
        f32x4 aZ = {0.f,0.f,0.f,0.f}, aR = {0.f,0.f,0.f,0.f}, aN = {0.f,0.f,0.f,0.f};

        if (isH) {
            if (t > 0) {
                const unsigned tagexp = (unsigned)t;
                const unsigned short* hp = hx3
                    + ((size_t)(((t - 1) & 1) * 4 + mq) * 8 + w) * 2048
                    + (size_t)l * 8;
                u32x4 q0 = {0,0,0,0}, q1 = {0,0,0,0}, q2 = {0,0,0,0}, q3 = {0,0,0,0};
                unsigned need = 0xFu;   // pending subtile bitmask (wave-uniform)
                while (true) {
                    unsigned f;
                    asm volatile("global_load_dword %0, %1, off sc0 sc1\n\t"
                                 "s_waitcnt vmcnt(0)"
                                 : "=v"(f) : "v"(fpal));
                    unsigned long long rdy = __ballot(f >= tagexp);
                    // pair si ready <=> lanes [8si, 8si+8) all set
                    if ((need & 1u) && (((rdy >> 0)  & 0xFFull) == 0xFFull)) {
                        asm volatile("global_load_dwordx4 %0, %1, off sc0 sc1"
                                     : "=&v"(q0) : "v"(hp));
                        need &= ~1u;
                    }
                    if ((need & 2u) && (((rdy >> 8)  & 0xFFull) == 0xFFull)) {
                        asm volatile("global_load_dwordx4 %0, %1, off offset:1024 sc0 sc1"
                                     : "=&v"(q1) : "v"(hp));
                        need &= ~2u;
                    }
                    if ((need & 4u) && (((rdy >> 16) & 0xFFull) == 0xFFull)) {
                        asm volatile("global_load_dwordx4 %0, %1, off offset:2048 sc0 sc1"
                                     : "=&v"(q2) : "v"(hp));
                        need &= ~4u;
                    }
                    if ((need & 8u) && (((rdy >> 24) & 0xFFull) == 0xFFull)) {
                        asm volatile("global_load_dwordx4 %0, %1, off offset:3072 sc0 sc1"
                                     : "=&v"(q3) : "v"(hp));
                        need &= ~8u;
                    }
                    if (!need) break;
                    __builtin_amdgcn_s_sleep(1);
                }
                // drain all data loads; "+v" ties MFMAs after this wait (rule 18)
                asm volatile("s_waitcnt vmcnt(0)"
                             : "+v"(q0), "+v"(q1), "+v"(q2), "+v"(q3));
                __builtin_amdgcn_sched_barrier(0);
                #define SUBT16(si, q) { \
                    half8 ah = __builtin_bit_cast(half8, (q)); \
                    aZ = MFMA_F16(ah, __builtin_bit_cast(half8, Bh[0][si]), aZ); \
                    aZ = MFMA_F16(ah, __builtin_bit_cast(half8, Bl[0][si]), aZ); \
                    aR = MFMA_F16(ah, __builtin_bit_cast(half8, Bh[1][si]), aR); \
                    aR = MFMA_F16(ah, __builtin_bit_cast(half8, Bl[1][si]), aR); \
                    aN = MFMA_F16(ah, __builtin_bit_cast(half8, Bh[2][si]), aN); \
                    aN = MFMA_F16(ah, __builtin_bit_cast(half8, Bl[2][si]), aN); }
                SUBT16(0, q0)
                SUBT16(1, q1)
                SUBT16(2, q2)
                SUBT16(3, q3)
                #undef SUBT16
            }
        } else {
            const float* xp = x + ((size_t)m * SEQ + t) * D_IN + kbase + koff;
            #pragma unroll
            for (int s = 0; s < 4; ++s) {
                f32x4 v0 = *(const f32x4*)(xp + 32 * s);
                f32x4 v1 = *(const f32x4*)(xp + 32 * s + 4);
                short8 ahi, alo;
                cvt8(v0, v1, ahi, alo);
                aZ = MFMA_BF16(ahi, Bh[0][s], aZ); aZ = MFMA_BF16(ahi, Bl[0][s], aZ);
                aZ = MFMA_BF16(alo, Bh[0][s], aZ);
                aR = MFMA_BF16(ahi, Bh[1][s], aR); aR = MFMA_BF16(ahi, Bl[1][s], aR);
                aR = MFMA_BF16(alo, Bh[1][s], aR);
                aN = MFMA_BF16(ahi, Bh[2][s], aN); aN = MFMA_BF16(ahi, Bl[2][s], aN);
                aN = MFMA_BF16(alo, Bh[2][s], aN);
            }
        }

        const int buf = t & 1;
        #pragma unroll
        for (int r = 0; r < 4; ++r) {
            red[buf][w][0][r][l] = aZ[r];
            red[buf][w][1][r][l] = aR[r];
            red[buf][w][2][r][l] = aN[r];
        }
        __syncthreads();   // red[t] published (single barrier per step)

        if (tid < 256) {
            float sz = 0.f, sr = 0.f, snx = 0.f, snh = 0.f;
            #pragma unroll
            for (int wv = 0; wv < 8; ++wv) {
                sz  += red[buf][wv][0][r2][l2];
                sr  += red[buf][wv][1][r2][l2];
                snh += red[buf][wv][2][r2][l2];
            }
            #pragma unroll
            for (int wv = 8; wv < 12; ++wv) {
                sz  += red[buf][wv][0][r2][l2];
                sr  += red[buf][wv][1][r2][l2];
                snx += red[buf][wv][2][r2][l2];
            }
            float z   = 1.f / (1.f + __expf(-(sz + bz)));
            float rr  = 1.f / (1.f + __expf(-(sr + br)));
            float pre = snx + bnb + rr * snh;
            float e2  = __expf(2.f * pre);
            float n   = 1.f - 2.f / (e2 + 1.f);
            float h   = (1.f - z) * n + z * hreg;
            hreg = h;

            // fragment-order fp16 data store -> drain (data at L3) -> flag
            unsigned hv = (unsigned)__builtin_bit_cast(unsigned short, (_Float16)h);
            unsigned short* hxp = hx3
                + ((size_t)((t & 1) * 4 + mq) * 8 + p_w) * 2048 + p_off;
            asm volatile("global_store_short %0, %1, off sc0 sc1"
                         :: "v"(hxp), "v"(hv) : "memory");
            asm volatile("s_waitcnt vmcnt(0)" ::: "memory");
            if ((tid & 63) == 0) {
                unsigned fv = (unsigned)(t + 1);
                asm volatile("global_store_dword %0, %1, off sc0 sc1"
                             :: "v"(fprod), "v"(fv) : "memory");
            }
            // archival fp32 writes: off critical path, normal cached stores
            hall[((size_t)be * SEQ + t) * HID + ce] = h;
            if (t == SEQ - 1) out[(size_t)be * HID + ce] = h;
        }
    }
}

extern "C" void kernel_launch(void* const* d_in, const int* in_sizes, int n_in,
                              void* d_out, int out_size, void* d_ws, size_t ws_size,
                              hipStream_t stream) {
    const float* x   = (const float*)d_in[0];
    const float* Win = (const float*)d_in[1];
    const float* bin = (const float*)d_in[2];
    const float* Wh  = (const float*)d_in[3];
    float* out = (float*)d_out;

    unsigned short* WBh = (unsigned short*)d_ws;                       // 9.44 MB
    unsigned short* WBl = (unsigned short*)d_ws + (size_t)WB_ELEMS;    // 9.44 MB
    const size_t hx_off = ((size_t)2 * WB_ELEMS * sizeof(unsigned short) + (1u << 20))
                          & ~((size_t)(1u << 20) - 1);                 // 1MB-aligned
    unsigned* flags      = (unsigned*)((char*)d_ws + hx_off);          // 4 KB
    unsigned short* hx3  = (unsigned short*)((char*)d_ws + hx_off + 65536); // 256 KB

    // zero flags every launch (replay-safe; hx3 needs no init - flag-gated)
    hipMemsetAsync(flags, 0, 4096, stream);
    hipLaunchKernelGGL(build_wt, dim3((WB_ELEMS + 255) / 256), dim3(256), 0, stream,
                       Win, Wh, WBh, WBl);
    hipLaunchKernelGGL(gru_persist, dim3(NBLK), dim3(BLOCK_T), 0, stream,
                       x, bin, WBh, WBl, out, hx3, flags);
}